// Round 1
// baseline (1719.400 us; speedup 1.0000x reference)
//
#include <hip/hip_runtime.h>

// N=20000, K=32, C=512, OUT=512 (fp32 in/out). Strategy:
//  k1: pack [W_l | W_r] -> bf16 W2[512][1024], bias = b_l + b_r
//  k2: agg = mean_k(neigh_x); A2[n] = [bf16(x[n]) | bf16(agg[n])]  (HBM-bound, 1.39 GB)
//  k3: out = A2 (Nx1024 bf16) @ W2^T + bias via mfma_f32_16x16x32_bf16, 128x128 tile

typedef __bf16 bf16x8 __attribute__((ext_vector_type(8)));
typedef float f32x4 __attribute__((ext_vector_type(4)));

__device__ __forceinline__ unsigned short f2bf(float f) {
    unsigned int u = __builtin_bit_cast(unsigned int, f);
    u += 0x7fffu + ((u >> 16) & 1u);   // RNE
    return (unsigned short)(u >> 16);
}

__device__ __forceinline__ void async_copy16(const void* g, void* l) {
    __builtin_amdgcn_global_load_lds(
        (__attribute__((address_space(1))) void*)(g),
        (__attribute__((address_space(3))) void*)(l),
        16, 0, 0);
}

// ---------------- kernel 1: weight pack ----------------
__global__ void pack_weights(const float* __restrict__ Wl, const float* __restrict__ bl,
                             const float* __restrict__ Wr, const float* __restrict__ br,
                             unsigned short* __restrict__ W2, float* __restrict__ bias)
{
    int t = blockIdx.x * 256 + threadIdx.x;          // 512*512 threads
    if (t < 512 * 512) {
        int o = t >> 9;
        int c = t & 511;
        W2[(size_t)o * 1024 + c]       = f2bf(Wl[t]);
        W2[(size_t)o * 1024 + 512 + c] = f2bf(Wr[t]);
    }
    if (t < 512) bias[t] = bl[t] + br[t];
}

// ---------------- kernel 2: mean-aggregate + bf16 convert ----------------
// one thread per (n, 4 channels); A2 row layout: [x bf16 (512) | agg bf16 (512)]
__global__ void agg_convert(const float* __restrict__ x, const float* __restrict__ nx,
                            unsigned short* __restrict__ A2, int N)
{
    int t = blockIdx.x * 256 + threadIdx.x;
    if (t >= N * 128) return;
    int n  = t >> 7;
    int c  = (t & 127) * 4;

    float4 xv = *(const float4*)&x[(size_t)n * 512 + c];

    const float* p = nx + (size_t)n * (32 * 512) + c;
    float4 s = make_float4(0.f, 0.f, 0.f, 0.f);
    #pragma unroll
    for (int k = 0; k < 32; k++) {
        float4 v = *(const float4*)(p + (size_t)k * 512);
        s.x += v.x; s.y += v.y; s.z += v.z; s.w += v.w;
    }
    const float inv = 1.0f / 32.0f;

    ushort4 xo, ao;
    xo.x = f2bf(xv.x); xo.y = f2bf(xv.y); xo.z = f2bf(xv.z); xo.w = f2bf(xv.w);
    ao.x = f2bf(s.x * inv); ao.y = f2bf(s.y * inv); ao.z = f2bf(s.z * inv); ao.w = f2bf(s.w * inv);

    *(ushort4*)&A2[(size_t)n * 1024 + c]       = xo;
    *(ushort4*)&A2[(size_t)n * 1024 + 512 + c] = ao;
}

// ---------------- kernel 3: bf16 MFMA GEMM ----------------
// out[M][512] = A[M][1024] * B[512][1024]^T + bias ; M ragged (clamp loads, guard stores)
// LDS layout: chunk q (16 B) at byte offset q*16; q = cc*128 + r  => element (r, k=cc*8+kk)
// at ushort index cc*1024 + r*8 + kk. Satisfies global_load_lds wave-uniform-base + lane*16
// and gives conflict-light ds_read_b128 (16 consecutive lanes sweep all 32 banks).
__global__ __launch_bounds__(256) void gemm_kernel(
    const unsigned short* __restrict__ A,   // [M][1024] bf16
    const unsigned short* __restrict__ B,   // [512][1024] bf16
    const float* __restrict__ bias,         // [512]
    float* __restrict__ out,                // [M][512]
    int M)
{
    __shared__ unsigned short As[4096];     // 8 KB
    __shared__ unsigned short Bs[4096];     // 8 KB

    const int tid  = threadIdx.x;
    const int row0 = blockIdx.y * 128;
    const int col0 = blockIdx.x * 128;
    const int wave = tid >> 6;
    const int lane = tid & 63;
    const int wm   = (wave >> 1) * 64;      // 0 or 64
    const int wn   = (wave & 1) * 64;       // 0 or 64
    const int m16  = lane & 15;
    const int quad = lane >> 4;             // 0..3

    f32x4 acc[4][4] = {};

    // staging: 512 chunks of 16 B per tile, 2 per thread
    const int q0 = tid, q1 = tid + 256;
    const int r0 = q0 & 127, cc0 = q0 >> 7;
    const int r1 = q1 & 127, cc1 = q1 >> 7;
    int ar0 = row0 + r0; if (ar0 >= M) ar0 = M - 1;
    int ar1 = row0 + r1; if (ar1 >= M) ar1 = M - 1;
    const unsigned short* pa0 = A + (size_t)ar0 * 1024 + cc0 * 8;
    const unsigned short* pa1 = A + (size_t)ar1 * 1024 + cc1 * 8;
    const unsigned short* pb0 = B + (size_t)(col0 + r0) * 1024 + cc0 * 8;
    const unsigned short* pb1 = B + (size_t)(col0 + r1) * 1024 + cc1 * 8;

    for (int kt = 0; kt < 1024; kt += 32) {
        __syncthreads();
        async_copy16(pa0 + kt, &As[q0 * 8]);
        async_copy16(pa1 + kt, &As[q1 * 8]);
        async_copy16(pb0 + kt, &Bs[q0 * 8]);
        async_copy16(pb1 + kt, &Bs[q1 * 8]);
        __syncthreads();

        bf16x8 af[4], bv[4];
        #pragma unroll
        for (int i = 0; i < 4; i++)
            af[i] = *(const bf16x8*)&As[quad * 1024 + (wm + i * 16 + m16) * 8];
        #pragma unroll
        for (int j = 0; j < 4; j++)
            bv[j] = *(const bf16x8*)&Bs[quad * 1024 + (wn + j * 16 + m16) * 8];

        #pragma unroll
        for (int i = 0; i < 4; i++)
            #pragma unroll
            for (int j = 0; j < 4; j++)
                acc[i][j] = __builtin_amdgcn_mfma_f32_16x16x32_bf16(af[i], bv[j], acc[i][j], 0, 0, 0);
    }

    // epilogue: D row = quad*4 + reg, col = lane&15  (verified m89/m91 mapping)
    #pragma unroll
    for (int j = 0; j < 4; j++) {
        const int c  = col0 + wn + j * 16 + m16;
        const float bvad = bias[c];
        #pragma unroll
        for (int i = 0; i < 4; i++) {
            const int rb = row0 + wm + i * 16 + quad * 4;
            #pragma unroll
            for (int r = 0; r < 4; r++) {
                const int rr = rb + r;
                if (rr < M)
                    out[(size_t)rr * 512 + c] = acc[i][j][r] + bvad;
            }
        }
    }
}

extern "C" void kernel_launch(void* const* d_in, const int* in_sizes, int n_in,
                              void* d_out, int out_size, void* d_ws, size_t ws_size,
                              hipStream_t stream)
{
    const float* x  = (const float*)d_in[0];
    const float* nx = (const float*)d_in[1];
    const float* Wl = (const float*)d_in[2];
    const float* bl = (const float*)d_in[3];
    const float* Wr = (const float*)d_in[4];
    const float* br = (const float*)d_in[5];
    float* out = (float*)d_out;
    const int N = in_sizes[0] / 512;

    char* ws = (char*)d_ws;
    unsigned short* W2 = (unsigned short*)ws;              // 1 MB  : 512x1024 bf16
    float* bias        = (float*)(ws + 1048576);           // 2 KB  : 512 f32
    unsigned short* A2 = (unsigned short*)(ws + 1050624);  // 40 MB : Nx1024 bf16 (16B aligned)

    pack_weights<<<1024, 256, 0, stream>>>(Wl, bl, Wr, br, W2, bias);
    agg_convert<<<(N * 128 + 255) / 256, 256, 0, stream>>>(x, nx, A2, N);
    gemm_kernel<<<dim3(512 / 128, (N + 127) / 128), 256, 0, stream>>>(A2, W2, bias, out, N);
}